// Round 13
// baseline (6620.934 us; speedup 1.0000x reference)
//
#include <hip/hip_runtime.h>
#include <hip/hip_bf16.h>
#include <cstdint>
#include <cstddef>

typedef __hip_bfloat16 bf16;
typedef unsigned short ushort;
typedef __attribute__((ext_vector_type(8))) short bf16x8;
typedef __attribute__((ext_vector_type(4))) float f32x4;

#define HDIM 256
#define NVOCAB 26
#define STR 264

// ---- workspace layout (float offsets) ----
// wsI[0..3]: flags ([1] = nonfinite count -> fp32 inputs). wsI[8..15]: global barrier slots.
#define OFF_BSUM  16
#define OFF_Z1    (OFF_BSUM+1024)
#define OFF_HH1   (OFF_Z1+1024)
#define OFF_H1    (OFF_HH1+1024)
#define OFF_C1    (OFF_H1+256)
#define OFF_WCH1  (OFF_C1+256)
#define OFF_BTF   (OFF_WCH1+256)
#define OFF_EWC   (OFF_BTF+256)          // [26][256] f32
#define OFF_P8    (OFF_EWC+6656)         // [26][1024] f32
#define OFF_SCB   (OFF_P8+26624)         // [32][256] ushort (scomb bf16)
#define OFF_O8B   (OFF_SCB+4096)         // [32][256] ushort (out8 bf16)
#define OFF_H2B   (OFF_O8B+4096)         // [32][256] ushort
#define OFF_C2T   (OFF_H2B+4096)         // [32][256] f32
#define OFF_HH2A  (OFF_C2T+8192)         // [32][1024] f32
#define OFF_H3B   (OFF_HH2A+32768)       // [704][256] ushort
#define OFF_C3T   (OFF_H3B+90112)        // [704][256] f32
#define OFF_HH3   (OFF_C3T+180224)       // [704][1024] f32
#define OFF_FRAG  (OFF_HH3+720896)       // ushort frag tables
#define OFF_SLABS (OFF_FRAG+327680)

__device__ __forceinline__ float sigmf(float x){ return 1.0f/(1.0f+__expf(-x)); }
__device__ __forceinline__ float tanhfast(float x){ return 1.0f - 2.0f/(__expf(2.0f*x)+1.0f); }
__device__ __forceinline__ ushort f2b(float x){ bf16 h = __float2bfloat16(x); return *(ushort*)&h; }
__device__ __forceinline__ float ldin(const void* p, int i, int f32){
  if (f32) return ((const float*)p)[i];
  unsigned int w = ((unsigned int)((const ushort*)p)[i]) << 16;
  return __uint_as_float(w);
}
__device__ __forceinline__ void ld8(const void* p, int i, int f32, float* o){
  if (f32){
    float4 a = *(const float4*)((const float*)p + i);
    float4 b = *(const float4*)((const float*)p + i + 4);
    o[0]=a.x;o[1]=a.y;o[2]=a.z;o[3]=a.w;o[4]=b.x;o[5]=b.y;o[6]=b.z;o[7]=b.w;
  } else {
    uint4 u = *(const uint4*)((const ushort*)p + i);
    unsigned w0=u.x,w1=u.y,w2=u.z,w3=u.w;
    o[0]=__uint_as_float(w0<<16); o[1]=__uint_as_float(w0&0xFFFF0000u);
    o[2]=__uint_as_float(w1<<16); o[3]=__uint_as_float(w1&0xFFFF0000u);
    o[4]=__uint_as_float(w2<<16); o[5]=__uint_as_float(w2&0xFFFF0000u);
    o[6]=__uint_as_float(w3<<16); o[7]=__uint_as_float(w3&0xFFFF0000u);
  }
}
__device__ __forceinline__ uint4 pack8(const ushort* h){
  uint4 u;
  u.x = (unsigned)h[0] | ((unsigned)h[1]<<16);
  u.y = (unsigned)h[2] | ((unsigned)h[3]<<16);
  u.z = (unsigned)h[4] | ((unsigned)h[5]<<16);
  u.w = (unsigned)h[6] | ((unsigned)h[7]<<16);
  return u;
}

// device-scope software barrier (all blocks co-resident; monotonic slot per use)
__device__ __forceinline__ void gbar(int* slot, int nblk){
  __syncthreads();
  if (threadIdx.x==0){
    __threadfence();
    __hip_atomic_fetch_add(slot, 1, __ATOMIC_ACQ_REL, __HIP_MEMORY_SCOPE_AGENT);
    while (__hip_atomic_load(slot, __ATOMIC_ACQUIRE, __HIP_MEMORY_SCOPE_AGENT) < nblk)
      __builtin_amdgcn_s_sleep(8);
  }
  __syncthreads();
  __threadfence();
}

__global__ void init_kernel(int* wsI){ if (threadIdx.x<16) wsI[threadIdx.x]=0; }

__global__ __launch_bounds__(256) void detect_kernel(int* wsI, const uint4* wih4){
  int c=0;
  for (int i = blockIdx.x*blockDim.x + threadIdx.x; i < 32768; i += gridDim.x*blockDim.x){
    uint4 u = wih4[i];
    unsigned w[4] = {u.x,u.y,u.z,u.w};
    #pragma unroll
    for (int j=0;j<4;j++){
      if ((w[j] & 0x7F80u) == 0x7F80u) c++;
      if ((w[j] & 0x7F800000u) == 0x7F800000u) c++;
    }
  }
  #pragma unroll
  for (int o=32;o>0;o>>=1) c += __shfl_xor(c,o,64);
  if ((threadIdx.x&63)==0 && c) atomicAdd(&wsI[1], c);
}

__global__ __launch_bounds__(256) void z1_kernel(
    float* __restrict__ wsf, const void* W_ih, const void* b_ih, const void* b_hh,
    const void* bt, const void* linit)
{
  const int f32 = ((const int*)wsf)[1] != 0;
  __shared__ float sx[256];
  int tid = threadIdx.x;
  int r = blockIdx.x*256 + tid;
  sx[tid] = ldin(linit, tid, f32);
  __syncthreads();
  float a = ldin(b_ih, r, f32) + ldin(b_hh, r, f32);
  wsf[OFF_BSUM + r] = a;
  float z = a;
  #pragma unroll 8
  for (int k=0;k<256;k+=8){
    float w[8]; ld8(W_ih, r*256+k, f32, w);
    #pragma unroll
    for (int j=0;j<8;j++) z += w[j]*sx[k+j];
  }
  wsf[OFF_Z1 + r] = z;
  if (blockIdx.x==0) wsf[OFF_BTF + tid] = ldin(bt, tid, f32);
}

__global__ __launch_bounds__(256) void h1_kernel(float* __restrict__ wsf){
  int e = threadIdx.x;
  float zi = wsf[OFF_Z1+e], zg = wsf[OFF_Z1+512+e], zo = wsf[OFF_Z1+768+e];
  float c1 = sigmf(zi)*tanhfast(zg);
  float h1 = sigmf(zo)*tanhfast(c1);
  wsf[OFF_H1+e]=h1; wsf[OFF_C1+e]=c1;
}

// blocks 0..3: hh1 rows; block 4: wch1 + scomb bf16 rows (needs EWC done)
__global__ __launch_bounds__(256) void hh1_kernel(float* __restrict__ wsf, const void* W_hh, const void* Wc){
  const int f32 = ((const int*)wsf)[1] != 0;
  __shared__ float sh1[256];
  int tid = threadIdx.x;
  sh1[tid] = wsf[OFF_H1+tid];
  __syncthreads();
  if (blockIdx.x < 4){
    int r = blockIdx.x*256 + tid;
    float z = wsf[OFF_BSUM + r];
    #pragma unroll 8
    for (int k=0;k<256;k+=8){
      float w[8]; ld8(W_hh, r*256+k, f32, w);
      #pragma unroll
      for (int j=0;j<8;j++) z += w[j]*sh1[k+j];
    }
    wsf[OFF_HH1 + r] = z;
  } else {
    float a = 0.f;
    #pragma unroll 8
    for (int k=0;k<256;k+=8){
      float w[8]; ld8(Wc, tid*512+k, f32, w);
      #pragma unroll
      for (int j=0;j<8;j++) a += w[j]*sh1[k+j];
    }
    wsf[OFF_WCH1 + tid] = a;
    ushort* SCB = (ushort*)(wsf + OFF_SCB);
    #pragma unroll 1
    for (int v32=0; v32<32; v32++){
      int v = v32 < NVOCAB ? v32 : NVOCAB-1;
      SCB[v32*256 + tid] = f2b(a + wsf[OFF_EWC + v*256 + tid]);
    }
  }
}

__global__ __launch_bounds__(256) void ewc_kernel(
    float* __restrict__ wsf, const void* Wc, const void* bc, const void* emb)
{
  const int f32 = ((const int*)wsf)[1] != 0;
  int v = blockIdx.x, i = threadIdx.x;
  __shared__ float se[256];
  se[i] = ldin(emb, v*256+i, f32);
  __syncthreads();
  float a = ldin(bc, i, f32);
  #pragma unroll 8
  for (int k=0;k<256;k+=8){
    float w[8]; ld8(Wc, i*512+256+k, f32, w);
    #pragma unroll
    for (int j=0;j<8;j++) a += w[j]*se[k+j];
  }
  wsf[OFF_EWC + v*256 + i] = a;
}

// A-fragment tables, vectorized
__global__ __launch_bounds__(256) void prep_kernel(
    float* __restrict__ wsf, const void* W_ih, const void* W_hh, const void* Wc, const void* Wt)
{
  const int f32 = ((const int*)wsf)[1] != 0;
  ushort* FWIH = (ushort*)(wsf + OFF_FRAG);
  ushort* FWHH = FWIH + 262144;
  ushort* FWC1 = FWHH + 262144;
  ushort* FWT  = FWC1 + 65536;
  int stride = gridDim.x*blockDim.x;
  int t0 = blockIdx.x*blockDim.x + threadIdx.x;
  for (int i=t0; i<32768; i+=stride){
    int c = i >> 6, L = i & 63;
    int mt = c>>3, ks = c&7;
    int m = (mt<<4) | (L&15);
    int k0 = (ks<<5) + ((L>>4)<<3);
    float w[8]; ushort h[8];
    ld8(W_ih, m*256+k0, f32, w);
    #pragma unroll
    for (int j=0;j<8;j++) h[j]=f2b(w[j]);
    *(uint4*)&FWIH[(c<<9)+(L<<3)] = pack8(h);
    ld8(W_hh, m*256+k0, f32, w);
    #pragma unroll
    for (int j=0;j<8;j++) h[j]=f2b(w[j]);
    *(uint4*)&FWHH[(c<<9)+(L<<3)] = pack8(h);
  }
  for (int i=t0; i<8192; i+=stride){
    int c = i >> 6, L = i & 63;
    int mt = c>>3, ks = c&7;
    int m = (mt<<4) | (L&15);
    int k0 = (ks<<5) + ((L>>4)<<3);
    float w[8]; ushort h[8];
    ld8(Wc, m*512+k0, f32, w);
    #pragma unroll
    for (int j=0;j<8;j++) h[j]=f2b(w[j]);
    *(uint4*)&FWC1[(c<<9)+(L<<3)] = pack8(h);
    ld8(Wt, m*256+k0, f32, w);
    #pragma unroll
    for (int j=0;j<8;j++) h[j]=f2b(w[j]);
    *(uint4*)&FWT[(c<<9)+(L<<3)] = pack8(h);
  }
}

// ---- tag8: tag = Wt@scomb + bt, log-softmax, out8 bf16 rows (26 vocab) ----
__global__ __launch_bounds__(256) void tag8_kernel(float* __restrict__ wsf){
  __shared__ float wred[4][16];
  const int tid=threadIdx.x, wv=tid>>6, lane=tid&63, ln15=lane&15, quad=lane>>4;
  const int nt = blockIdx.x;
  const ushort* FWT = (const ushort*)(wsf + OFF_FRAG) + 262144 + 262144 + 65536;
  const ushort* SCB = (const ushort*)(wsf + OFF_SCB);
  ushort* O8B = (ushort*)(wsf + OFF_O8B);
  const int row = nt*16 + ln15;

  f32x4 tg[4];
  #pragma unroll 1
  for (int p=0; p<4; p++){
    const int mt = wv*4 + p;
    tg[p] = (f32x4){0.f,0.f,0.f,0.f};
    #pragma unroll
    for (int ks=0; ks<8; ks++){
      bf16x8 a = *(const bf16x8*)&FWT[((mt*8+ks)<<9) + (lane<<3)];
      bf16x8 b = *(const bf16x8*)&SCB[row*256 + ks*32 + quad*8];
      tg[p] = __builtin_amdgcn_mfma_f32_16x16x32_bf16(a, b, tg[p], 0,0,0);
    }
    float4 bt4 = *(const float4*)&wsf[OFF_BTF + mt*16 + quad*4];
    #pragma unroll
    for (int r=0; r<4; r++) tg[p][r] += ((const float*)&bt4)[r];
  }

  float mx = -3.0e38f;
  #pragma unroll
  for (int p=0; p<4; p++)
    #pragma unroll
    for (int r=0; r<4; r++) mx = fmaxf(mx, tg[p][r]);
  mx = fmaxf(mx, __shfl_xor(mx, 16, 64));
  mx = fmaxf(mx, __shfl_xor(mx, 32, 64));
  wred[wv][ln15] = mx;
  __syncthreads();
  float gmx = fmaxf(fmaxf(wred[0][ln15], wred[1][ln15]), fmaxf(wred[2][ln15], wred[3][ln15]));
  __syncthreads();
  float s = 0.f;
  #pragma unroll
  for (int p=0; p<4; p++)
    #pragma unroll
    for (int r=0; r<4; r++) s += __expf(tg[p][r] - gmx);
  s += __shfl_xor(s, 16, 64);
  s += __shfl_xor(s, 32, 64);
  wred[wv][ln15] = s;
  __syncthreads();
  float gs = (wred[0][ln15]+wred[1][ln15]) + (wred[2][ln15]+wred[3][ln15]);
  float lz = gmx + __logf(gs);

  #pragma unroll
  for (int p=0; p<4; p++){
    int m = (wv*4+p)*16 + quad*4;
    ushort ob[4];
    #pragma unroll
    for (int r=0; r<4; r++) ob[r] = f2b(tg[p][r] - lz);
    uint2 uu;
    uu.x = (unsigned)ob[0] | ((unsigned)ob[1]<<16);
    uu.y = (unsigned)ob[2] | ((unsigned)ob[3]<<16);
    *(uint2*)&O8B[row*256 + m] = uu;
  }
}

// ---- p8: P8[v] = W_ih @ out8[v] via MFMA ----
__global__ __launch_bounds__(64) void p8_kernel(float* __restrict__ wsf){
  const int nt = blockIdx.x >> 4, eb = blockIdx.x & 15;
  const int lane = threadIdx.x, ln15 = lane & 15, quad = lane >> 4;
  const ushort* FWIH = (const ushort*)(wsf + OFF_FRAG);
  const ushort* O8B  = (const ushort*)(wsf + OFF_O8B);
  const int row = nt*16 + ln15;

  f32x4 acc[4];
  #pragma unroll
  for (int g=0; g<4; g++) acc[g] = (f32x4){0.f,0.f,0.f,0.f};
  #pragma unroll
  for (int ks=0; ks<8; ks++){
    bf16x8 b = *(const bf16x8*)&O8B[row*256 + ks*32 + quad*8];
    #pragma unroll
    for (int g=0; g<4; g++){
      int mt = g*16 + eb;
      bf16x8 a = *(const bf16x8*)&FWIH[((mt*8+ks)<<9) + (lane<<3)];
      acc[g] = __builtin_amdgcn_mfma_f32_16x16x32_bf16(a, b, acc[g], 0,0,0);
    }
  }
  if (row < NVOCAB){
    #pragma unroll
    for (int g=0; g<4; g++)
      *(float4*)&wsf[OFF_P8 + row*1024 + g*256 + eb*16 + quad*4] =
        (float4){acc[g][0], acc[g][1], acc[g][2], acc[g][3]};
  }
}

// ---- t2 table ----
__global__ __launch_bounds__(256) void t2tab_kernel(float* __restrict__ wsf){
  int a = blockIdx.x, e = threadIdx.x;
  const float* P8a = wsf + OFF_P8 + (size_t)a*1024;
  float zi = wsf[OFF_HH1+e]     + P8a[e];
  float zf = wsf[OFF_HH1+256+e] + P8a[256+e];
  float zg = wsf[OFF_HH1+512+e] + P8a[512+e];
  float zo = wsf[OFF_HH1+768+e] + P8a[768+e];
  float cn = sigmf(zf)*wsf[OFF_C1+e] + sigmf(zi)*tanhfast(zg);
  ((ushort*)(wsf+OFF_H2B))[a*256+e] = f2b(sigmf(zo)*tanhfast(cn));
  wsf[OFF_C2T + a*256 + e] = cn;
}

// ---- hhmat: Out[r] = bsum + W_hh @ Hrows[r] ----
__global__ __launch_bounds__(64) void hhmat_kernel(
    float* __restrict__ wsf, const ushort* __restrict__ Hrows,
    float* __restrict__ Out, int R)
{
  const int nt = blockIdx.x >> 4, eb = blockIdx.x & 15;
  const int lane = threadIdx.x, ln15 = lane & 15, quad = lane >> 4;
  const ushort* FWHH = (const ushort*)(wsf + OFF_FRAG) + 262144;
  int row = nt*16 + ln15;
  int rowc = row < R ? row : R-1;

  f32x4 acc[4];
  #pragma unroll
  for (int g=0; g<4; g++) acc[g] = (f32x4){0.f,0.f,0.f,0.f};
  #pragma unroll
  for (int ks=0; ks<8; ks++){
    bf16x8 b = *(const bf16x8*)&Hrows[rowc*256 + ks*32 + quad*8];
    #pragma unroll
    for (int g=0; g<4; g++){
      int mt = g*16 + eb;
      bf16x8 a = *(const bf16x8*)&FWHH[((mt*8+ks)<<9) + (lane<<3)];
      acc[g] = __builtin_amdgcn_mfma_f32_16x16x32_bf16(a, b, acc[g], 0,0,0);
    }
  }
  if (row < R){
    #pragma unroll
    for (int g=0; g<4; g++){
      int m = g*256 + eb*16 + quad*4;
      float4 bs = *(const float4*)&wsf[OFF_BSUM + m];
      *(float4*)&Out[(size_t)row*1024 + m] =
        (float4){acc[g][0]+bs.x, acc[g][1]+bs.y, acc[g][2]+bs.z, acc[g][3]+bs.w};
    }
  }
}

// ---- t3 table ----
__global__ __launch_bounds__(256) void t3tab_kernel(float* __restrict__ wsf){
  int p = blockIdx.x;
  int a = p / 26, b = p - a*26;
  int e = threadIdx.x;
  const float* HA = wsf + OFF_HH2A + (size_t)a*1024;
  const float* PB = wsf + OFF_P8   + (size_t)b*1024;
  float zi = HA[e]     + PB[e];
  float zf = HA[256+e] + PB[256+e];
  float zg = HA[512+e] + PB[512+e];
  float zo = HA[768+e] + PB[768+e];
  float cn = sigmf(zf)*wsf[OFF_C2T + a*256 + e] + sigmf(zi)*tanhfast(zg);
  ((ushort*)(wsf+OFF_H3B))[p*256+e] = f2b(sigmf(zo)*tanhfast(cn));
  wsf[OFF_C3T + p*256 + e] = cn;
}

// ---- level-7 kernel: t1/t2/t3 tabulated; t3=gather-gate, t4=one W_hh MFMA ----
__global__ __launch_bounds__(1024) void level7_kernel(
    const float* __restrict__ wsf, const int* __restrict__ idents,
    int offL, int offC, int nNodes, int nChild, ushort* __restrict__ OutNext)
{
  __shared__ __align__(16) ushort Hlds[2][16*STR];
  __shared__ float wred[16][16];
  __shared__ int sid[16], sid4[64];
  const int tid=threadIdx.x, wv=tid>>6, lane=tid&63, ln15=lane&15, quad=lane>>4;
  const int j0 = blockIdx.x*16;
  const ushort* FWHH = (const ushort*)(wsf+OFF_FRAG)+262144;
  const ushort* FWC1 = FWHH+262144;
  const ushort* FWT  = FWC1+65536;
  const float* P8 = wsf+OFF_P8;
  const float* EWcP = wsf+OFF_EWC;

  if (tid<16){ int nd=j0+tid; if(nd>=nNodes) nd=nNodes-1; sid[tid]=idents[offL+nd]; }
  if (tid<64){ int ci=j0*4+tid; if(ci>=nChild) ci=nChild-1; sid4[tid]=idents[offC+ci]; }
  __syncthreads();

  const int eb = wv*16;
  const int ia=sid4[ln15*4], ib=sid4[ln15*4+1], ic=sid4[ln15*4+2], idd=sid4[ln15*4+3];
  const int pp = ia*26+ib;

  f32x4 creg;
  {
    const float* HH3p = wsf + OFF_HH3 + (size_t)pp*1024;
    const float* P8c  = P8 + (size_t)ic*1024;
    float4 cp4 = *(const float4*)&wsf[OFF_C3T + (size_t)pp*256 + eb + quad*4];
    float z[4][4];
    #pragma unroll
    for (int g=0; g<4; g++){
      float4 hv = *(const float4*)&HH3p[g*256 + eb + quad*4];
      float4 pv = *(const float4*)&P8c[g*256 + eb + quad*4];
      z[g][0]=hv.x+pv.x; z[g][1]=hv.y+pv.y; z[g][2]=hv.z+pv.z; z[g][3]=hv.w+pv.w;
    }
    ushort hb[4];
    #pragma unroll
    for (int r=0; r<4; r++){
      float cn = sigmf(z[1][r])*((const float*)&cp4)[r] + sigmf(z[0][r])*tanhfast(z[2][r]);
      creg[r]=cn;
      hb[r]=f2b(sigmf(z[3][r])*tanhfast(cn));
    }
    uint2 uu;
    uu.x = (unsigned)hb[0] | ((unsigned)hb[1]<<16);
    uu.y = (unsigned)hb[2] | ((unsigned)hb[3]<<16);
    *(uint2*)&Hlds[0][ln15*STR + eb + quad*4] = uu;
  }
  __syncthreads();

  {
    f32x4 acc[4];
    #pragma unroll
    for (int g=0; g<4; g++) acc[g] = (f32x4){0.f,0.f,0.f,0.f};
    #pragma unroll
    for (int ks=0; ks<8; ks++){
      bf16x8 bh = *(const bf16x8*)&Hlds[0][ln15*STR + ks*32 + quad*8];
      #pragma unroll
      for (int g=0; g<4; g++){
        bf16x8 a = *(const bf16x8*)&FWHH[(((g*16+wv)*8+ks)<<9) + (lane<<3)];
        acc[g] = __builtin_amdgcn_mfma_f32_16x16x32_bf16(a, bh, acc[g], 0,0,0);
      }
    }
    const float* P8d = P8 + (size_t)idd*1024;
    #pragma unroll
    for (int g=0; g<4; g++){
      float4 bg = *(const float4*)&wsf[OFF_BSUM + g*256 + eb + quad*4];
      float4 xg = *(const float4*)&P8d[g*256 + eb + quad*4];
      acc[g][0]+=bg.x+xg.x; acc[g][1]+=bg.y+xg.y; acc[g][2]+=bg.z+xg.z; acc[g][3]+=bg.w+xg.w;
    }
    ushort hb[4];
    #pragma unroll
    for (int r=0; r<4; r++){
      float cn = sigmf(acc[1][r])*creg[r] + sigmf(acc[0][r])*tanhfast(acc[2][r]);
      hb[r]=f2b(sigmf(acc[3][r])*tanhfast(cn));
    }
    uint2 uu;
    uu.x = (unsigned)hb[0] | ((unsigned)hb[1]<<16);
    uu.y = (unsigned)hb[2] | ((unsigned)hb[3]<<16);
    *(uint2*)&Hlds[1][ln15*STR + eb + quad*4] = uu;
  }
  __syncthreads();

  {
    f32x4 ac = (f32x4){0.f,0.f,0.f,0.f};
    #pragma unroll
    for (int ks=0; ks<8; ks++){
      bf16x8 a = *(const bf16x8*)&FWC1[((wv*8+ks)<<9) + (lane<<3)];
      bf16x8 b = *(const bf16x8*)&Hlds[1][ln15*STR + ks*32 + quad*8];
      ac = __builtin_amdgcn_mfma_f32_16x16x32_bf16(a, b, ac, 0,0,0);
    }
    float4 ew = *(const float4*)&EWcP[(size_t)sid[ln15]*256 + wv*16 + quad*4];
    ushort cb[4];
    #pragma unroll
    for (int r=0; r<4; r++) cb[r] = f2b(ac[r] + ((const float*)&ew)[r]);
    uint2 uu;
    uu.x = (unsigned)cb[0] | ((unsigned)cb[1]<<16);
    uu.y = (unsigned)cb[2] | ((unsigned)cb[3]<<16);
    *(uint2*)&Hlds[0][ln15*STR + wv*16 + quad*4] = uu;
  }
  __syncthreads();

  f32x4 tg = (f32x4){0.f,0.f,0.f,0.f};
  #pragma unroll
  for (int ks=0; ks<8; ks++){
    bf16x8 a = *(const bf16x8*)&FWT[((wv*8+ks)<<9) + (lane<<3)];
    bf16x8 b = *(const bf16x8*)&Hlds[0][ln15*STR + ks*32 + quad*8];
    tg = __builtin_amdgcn_mfma_f32_16x16x32_bf16(a, b, tg, 0,0,0);
  }
  {
    float4 bt4 = *(const float4*)&wsf[OFF_BTF + wv*16 + quad*4];
    #pragma unroll
    for (int r=0; r<4; r++) tg[r] += ((const float*)&bt4)[r];
  }

  float mx = fmaxf(fmaxf(tg[0],tg[1]), fmaxf(tg[2],tg[3]));
  mx = fmaxf(mx, __shfl_xor(mx, 16, 64));
  mx = fmaxf(mx, __shfl_xor(mx, 32, 64));
  wred[wv][ln15] = mx;
  __syncthreads();
  float gmx = wred[0][ln15];
  #pragma unroll
  for (int w=1; w<16; w++) gmx = fmaxf(gmx, wred[w][ln15]);
  __syncthreads();
  float s = __expf(tg[0]-gmx) + __expf(tg[1]-gmx) + __expf(tg[2]-gmx) + __expf(tg[3]-gmx);
  s += __shfl_xor(s, 16, 64);
  s += __shfl_xor(s, 32, 64);
  wred[wv][ln15] = s;
  __syncthreads();
  float gs = 0.f;
  #pragma unroll
  for (int w=0; w<16; w++) gs += wred[w][ln15];
  float lz = gmx + __logf(gs);

  int node = j0 + ln15;
  if (node < nNodes){
    ushort ob[4];
    #pragma unroll
    for (int r=0; r<4; r++) ob[r] = f2b(tg[r] - lz);
    uint2 uu;
    uu.x = (unsigned)ob[0] | ((unsigned)ob[1]<<16);
    uu.y = (unsigned)ob[2] | ((unsigned)ob[3]<<16);
    *(uint2*)&OutNext[(size_t)node*256 + wv*16 + quad*4] = uu;
  }
}

// ---- mega tail: ALL of L6..L0 in one launch; 256 blocks x 256 threads.
// Each block owns 16 nodes/level (r5 fused body: 4 waves x 4 p-passes).
// Global software barrier between levels (all 256 blocks co-resident).
__global__ __launch_bounds__(256) void tail_kernel(
    float* __restrict__ wsf, ushort* __restrict__ slabA, ushort* __restrict__ slabB,
    const int* __restrict__ idents, void* __restrict__ dout)
{
  __shared__ __align__(16) ushort Hlds[2][16*STR];
  __shared__ __align__(16) ushort Xlds[16*STR];
  __shared__ float wred[4][16];
  __shared__ int sid[16];

  const int tid=threadIdx.x, wv=tid>>6, lane=tid&63, ln15=lane&15, quad=lane>>4;
  const int bi = blockIdx.x;
  int* bar = ((int*)wsf) + 8;

  const ushort* FWIH = (const ushort*)(wsf + OFF_FRAG);
  const ushort* FWHH = FWIH + 262144;
  const ushort* FWC1 = FWHH + 262144;
  const ushort* FWT  = FWC1 + 65536;
  const float*  EWcP = wsf + OFF_EWC;

  const int nArr[7]   = {4096,1024,256,64,16,4,1};
  const int offArr[7] = {1365,341,85,21,5,1,0};

  #pragma unroll 1
  for (int lvl=0; lvl<7; lvl++){
    const int n = nArr[lvl], offL = offArr[lvl];
    const ushort* OutPrev = (lvl&1) ? slabB : slabA;
    ushort*       OutNext = (lvl&1) ? slabA : slabB;
    const bool last = (lvl==6);
    const int nblkL = (n+15)>>4;

    if (bi < nblkL){
      const int j0 = bi*16;
      if (tid<16){ int nd=j0+tid; if(nd>=n) nd=n-1; sid[tid]=idents[offL+nd]; }
      f32x4 creg[4];

      #pragma unroll 1
      for (int t=1; t<=4; t++){
        for (int i=tid; i<512; i+=256){
          int nn=i>>5, off=i&31;
          int node=j0+nn; if(node>=n) node=n-1;
          uint4 v = ((const uint4*)OutPrev)[((size_t)node*4+(t-1))*32+off];
          *(uint4*)&Xlds[nn*STR+off*8]=v;
        }
        __syncthreads();
        const int rb=(t-1)&1, wb=t&1;

        #pragma unroll 1
        for (int p=0; p<4; p++){
          const int eb=(wv*4+p)*16;
          f32x4 acc[4];
          #pragma unroll
          for (int g=0;g<4;g++) acc[g]=(f32x4){0.f,0.f,0.f,0.f};
          if (t>=2){
            #pragma unroll
            for (int ks=0; ks<8; ks++){
              bf16x8 bh = *(const bf16x8*)&Hlds[rb][ln15*STR + ks*32 + quad*8];
              #pragma unroll
              for (int g=0; g<4; g++){
                int mt = g*16 + wv*4 + p;
                bf16x8 a = *(const bf16x8*)&FWHH[((mt*8+ks)<<9) + (lane<<3)];
                acc[g] = __builtin_amdgcn_mfma_f32_16x16x32_bf16(a, bh, acc[g], 0,0,0);
              }
            }
          }
          #pragma unroll
          for (int ks=0; ks<8; ks++){
            bf16x8 bx = *(const bf16x8*)&Xlds[ln15*STR + ks*32 + quad*8];
            #pragma unroll
            for (int g=0; g<4; g++){
              int mt = g*16 + wv*4 + p;
              bf16x8 a = *(const bf16x8*)&FWIH[((mt*8+ks)<<9) + (lane<<3)];
              acc[g] = __builtin_amdgcn_mfma_f32_16x16x32_bf16(a, bx, acc[g], 0,0,0);
            }
          }
          const float* baseP = wsf + ((t==1) ? OFF_HH1 : OFF_BSUM);
          #pragma unroll
          for (int g=0; g<4; g++){
            float4 bg = *(const float4*)&baseP[g*256 + eb + quad*4];
            acc[g][0]+=bg.x; acc[g][1]+=bg.y; acc[g][2]+=bg.z; acc[g][3]+=bg.w;
          }
          f32x4 cp;
          if (t==1){
            float4 cc = *(const float4*)&wsf[OFF_C1 + eb + quad*4];
            cp = (f32x4){cc.x,cc.y,cc.z,cc.w};
          } else cp = creg[p];
          ushort hb[4];
          #pragma unroll
          for (int r=0; r<4; r++){
            float cn = sigmf(acc[1][r])*cp[r] + sigmf(acc[0][r])*tanhfast(acc[2][r]);
            creg[p][r] = cn;
            hb[r] = f2b(sigmf(acc[3][r])*tanhfast(cn));
          }
          uint2 uu;
          uu.x = (unsigned)hb[0] | ((unsigned)hb[1]<<16);
          uu.y = (unsigned)hb[2] | ((unsigned)hb[3]<<16);
          *(uint2*)&Hlds[wb][ln15*STR + eb + quad*4] = uu;
        }
        __syncthreads();
      }

      // combine = Wc1@h + EWc[id]  (h in Hlds[0] -> comb in Hlds[1])
      #pragma unroll 1
      for (int p=0; p<4; p++){
        const int mt = wv*4 + p;
        f32x4 ac = (f32x4){0.f,0.f,0.f,0.f};
        #pragma unroll
        for (int ks=0; ks<8; ks++){
          bf16x8 a = *(const bf16x8*)&FWC1[((mt*8+ks)<<9) + (lane<<3)];
          bf16x8 b = *(const bf16x8*)&Hlds[0][ln15*STR + ks*32 + quad*8];
          ac = __builtin_amdgcn_mfma_f32_16x16x32_bf16(a, b, ac, 0,0,0);
        }
        float4 ew = *(const float4*)&EWcP[(size_t)sid[ln15]*256 + mt*16 + quad*4];
        ushort cb[4];
        #pragma unroll
        for (int r=0; r<4; r++) cb[r] = f2b(ac[r] + ((const float*)&ew)[r]);
        uint2 uu;
        uu.x = (unsigned)cb[0] | ((unsigned)cb[1]<<16);
        uu.y = (unsigned)cb[2] | ((unsigned)cb[3]<<16);
        *(uint2*)&Hlds[1][ln15*STR + mt*16 + quad*4] = uu;
      }
      __syncthreads();

      // tag
      f32x4 tg[4];
      #pragma unroll 1
      for (int p=0; p<4; p++){
        const int mt = wv*4 + p;
        tg[p] = (f32x4){0.f,0.f,0.f,0.f};
        #pragma unroll
        for (int ks=0; ks<8; ks++){
          bf16x8 a = *(const bf16x8*)&FWT[((mt*8+ks)<<9) + (lane<<3)];
          bf16x8 b = *(const bf16x8*)&Hlds[1][ln15*STR + ks*32 + quad*8];
          tg[p] = __builtin_amdgcn_mfma_f32_16x16x32_bf16(a, b, tg[p], 0,0,0);
        }
        float4 bt4 = *(const float4*)&wsf[OFF_BTF + mt*16 + quad*4];
        #pragma unroll
        for (int r=0; r<4; r++) tg[p][r] += ((const float*)&bt4)[r];
      }

      // log-softmax
      float mx = -3.0e38f;
      #pragma unroll
      for (int p=0; p<4; p++)
        #pragma unroll
        for (int r=0; r<4; r++) mx = fmaxf(mx, tg[p][r]);
      mx = fmaxf(mx, __shfl_xor(mx, 16, 64));
      mx = fmaxf(mx, __shfl_xor(mx, 32, 64));
      wred[wv][ln15] = mx;
      __syncthreads();
      float gmx = fmaxf(fmaxf(wred[0][ln15], wred[1][ln15]), fmaxf(wred[2][ln15], wred[3][ln15]));
      __syncthreads();
      float s = 0.f;
      #pragma unroll
      for (int p=0; p<4; p++)
        #pragma unroll
        for (int r=0; r<4; r++) s += __expf(tg[p][r] - gmx);
      s += __shfl_xor(s, 16, 64);
      s += __shfl_xor(s, 32, 64);
      wred[wv][ln15] = s;
      __syncthreads();
      float gs = (wred[0][ln15]+wred[1][ln15]) + (wred[2][ln15]+wred[3][ln15]);
      float lz = gmx + __logf(gs);

      if (last){
        if (ln15 == 0){
          const int f32o = ((const int*)wsf)[1] != 0;
          #pragma unroll
          for (int p=0; p<4; p++){
            #pragma unroll
            for (int r=0; r<4; r++){
              int m = (wv*4+p)*16 + quad*4 + r;
              float v = tg[p][r] - lz;
              if (f32o) ((float*)dout)[m] = v;
              else      ((ushort*)dout)[m] = f2b(v);
            }
          }
        }
      } else {
        int onode = j0 + ln15;
        if (onode < n){
          #pragma unroll
          for (int p=0; p<4; p++){
            int m = (wv*4+p)*16 + quad*4;
            ushort ob[4];
            #pragma unroll
            for (int r=0; r<4; r++) ob[r] = f2b(tg[p][r] - lz);
            uint2 uu;
            uu.x = (unsigned)ob[0] | ((unsigned)ob[1]<<16);
            uu.y = (unsigned)ob[2] | ((unsigned)ob[3]<<16);
            *(uint2*)&OutNext[(size_t)onode*256 + m] = uu;
          }
        }
      }
    }
    if (lvl < 6) gbar(&bar[lvl], gridDim.x);
  }
}

extern "C" void kernel_launch(void* const* d_in, const int* in_sizes, int n_in,
                              void* d_out, int out_size, void* d_ws, size_t ws_size,
                              hipStream_t stream)
{
  (void)in_sizes; (void)n_in; (void)out_size; (void)ws_size;
  const int* idents = (const int*)d_in[0];
  const void* emb   = d_in[1];
  const void* W_ih  = d_in[2];
  const void* W_hh  = d_in[3];
  const void* b_ih  = d_in[4];
  const void* b_hh  = d_in[5];
  const void* Wc    = d_in[6];
  const void* bc    = d_in[7];
  const void* Wt    = d_in[8];
  const void* bt    = d_in[9];
  const void* linit = d_in[10];

  float* wsf = (float*)d_ws;
  ushort* slabA = (ushort*)(wsf + OFF_SLABS);
  ushort* slabB = slabA + (size_t)16384*256;

  init_kernel  <<<1, 64, 0, stream>>>((int*)d_ws);
  detect_kernel<<<16, 256, 0, stream>>>((int*)d_ws, (const uint4*)W_ih);
  z1_kernel    <<<4, 256, 0, stream>>>(wsf, W_ih, b_ih, b_hh, bt, linit);
  prep_kernel  <<<128, 256, 0, stream>>>(wsf, W_ih, W_hh, Wc, Wt);
  ewc_kernel   <<<NVOCAB, 256, 0, stream>>>(wsf, Wc, bc, emb);
  h1_kernel    <<<1, 256, 0, stream>>>(wsf);
  hh1_kernel   <<<5, 256, 0, stream>>>(wsf, W_hh, Wc);
  tag8_kernel  <<<2, 256, 0, stream>>>(wsf);
  p8_kernel    <<<32, 64, 0, stream>>>(wsf);

  t2tab_kernel <<<NVOCAB, 256, 0, stream>>>(wsf);
  hhmat_kernel <<<32, 64, 0, stream>>>(wsf, (const ushort*)(wsf+OFF_H2B), wsf+OFF_HH2A, NVOCAB);
  t3tab_kernel <<<NVOCAB*NVOCAB, 256, 0, stream>>>(wsf);
  hhmat_kernel <<<((NVOCAB*NVOCAB+15)/16)*16, 64, 0, stream>>>(wsf, (const ushort*)(wsf+OFF_H3B), wsf+OFF_HH3, NVOCAB*NVOCAB);

  level7_kernel<<<1024,1024,0,stream>>>(wsf, idents, 5461, 21845, 16384, 65536, slabA);

  // L6..L0 in ONE kernel with global software barriers between levels
  tail_kernel  <<<256, 256, 0, stream>>>(wsf, slabA, slabB, idents, d_out);
}